// Round 5
// baseline (291.344 us; speedup 1.0000x reference)
//
#include <hip/hip_runtime.h>

#define B_  8
#define C_  64
#define T_  12
#define N_  512
#define E_  8192
#define H_  4
#define CO_ 64
#define G_  (B_ * T_)        // 96
#define EP_ (E_ + N_)        // 8704 edges incl self loops

typedef __bf16 bf16x8 __attribute__((ext_vector_type(8)));
typedef unsigned short usx8 __attribute__((ext_vector_type(8)));
typedef float  f32x4  __attribute__((ext_vector_type(4)));

static __device__ __forceinline__ unsigned short f2bf(float f) {
    unsigned int u = __float_as_uint(f);
    return (unsigned short)((u + 0x7fffu + ((u >> 16) & 1u)) >> 16);   // RNE
}
static __device__ __forceinline__ float bf2f(unsigned short s) {
    return __uint_as_float(((unsigned int)s) << 16);
}

// ---------------- K1: Wsrc/Wdst reduction + CSR build + W-frag pre-swizzle ------
__global__ __launch_bounds__(512) void k_csr(
    const int* __restrict__ ei, const float* __restrict__ W,
    const float* __restrict__ att_src, const float* __restrict__ att_dst,
    float* __restrict__ Wsrc, float* __restrict__ Wdst,
    int* __restrict__ off, int* __restrict__ srclist,
    unsigned short* __restrict__ Wfrag)
{
    __shared__ int lcnt[512];
    __shared__ int lscan[512];
    int tid = threadIdx.x;

    // phase 0a: Wsrc[c,h] = W[c, h*64:]·att_src[h,:]  (tid<256)
    if (tid < 256) {
        int c = tid & 63, hh = tid >> 6;
        float s1 = 0.f, s2 = 0.f;
        for (int co = 0; co < 64; ++co) {
            float w = W[c * 256 + hh * 64 + co];
            s1 += w * att_src[hh * 64 + co];
            s2 += w * att_dst[hh * 64 + co];
        }
        Wsrc[c * 4 + hh] = s1;
        Wdst[c * 4 + hh] = s2;
    }

    // phase 0b: W -> bf16 B-fragment layout for Wcat[k=h*64+c][co]
    // Wfrag[((ks*4+nt)*64 + l)*8 + j],  ks=k>>5, j=k&7, l=((k>>3)&3)*16+(co&15), nt=co>>4
    for (int idx = tid; idx < 64 * 256; idx += 512) {
        int c  = idx >> 8, r = idx & 255;
        int hh = r >> 6,  co = r & 63;
        int k  = hh * 64 + c;
        int ks = k >> 5, kq = (k >> 3) & 3, j = k & 7;
        int nt = co >> 4, l = kq * 16 + (co & 15);
        Wfrag[(size_t)((ks * 4 + nt) * 64 + l) * 8 + j] = f2bf(W[idx]);
    }

    lcnt[tid] = 1;                        // self loop
    __syncthreads();
    for (int e = tid; e < E_; e += 512)
        atomicAdd(&lcnt[ei[E_ + e]], 1);
    __syncthreads();
    int v = lcnt[tid];
    lscan[tid] = v;
    __syncthreads();
    for (int d = 1; d < 512; d <<= 1) {
        int val = (tid >= d) ? lscan[tid - d] : 0;
        __syncthreads();
        lscan[tid] += val;
        __syncthreads();
    }
    int excl = lscan[tid] - v;
    off[tid] = excl;
    if (tid == 511) off[512] = lscan[511];
    lcnt[tid] = excl;                     // repurpose as cursor
    __syncthreads();
    for (int e = tid; e < EP_; e += 512) {
        int d, s;
        if (e < E_) { d = ei[E_ + e]; s = ei[e]; }
        else        { d = e - E_;     s = d; }
        int pos = atomicAdd(&lcnt[d], 1);
        srclist[pos] = s;
    }
}

// ---------------- K2: xt transpose + as_t/ad_t logit dots ([h][n][g] layout) ----
__global__ __launch_bounds__(256) void k_prep(
    const float* __restrict__ x, const float* __restrict__ Wsrc,
    const float* __restrict__ Wdst,
    float* __restrict__ xt, float* __restrict__ as_t, float* __restrict__ ad_t)
{
    __shared__ float xs[64][65];
    int bid  = blockIdx.x;                 // 768 = 8 xcd * 12 g * 8 tiles
    int xcd  = bid & 7;
    int r    = bid >> 3;                   // 0..95
    int g    = xcd * 12 + (r >> 3);
    int tile = r & 7;
    int b    = g / T_, t = g - b * T_;
    int n0   = tile * 64;
    int tid  = threadIdx.x;
    int lane = tid & 63, q = tid >> 6;

    #pragma unroll
    for (int i = 0; i < 16; ++i) {
        int c = q + i * 4;
        xs[c][lane] = x[((size_t)(b * C_ + c) * T_ + t) * N_ + n0 + lane];
    }
    __syncthreads();

    float s1 = 0.f, s2 = 0.f;
    for (int c = 0; c < 64; ++c) {
        float v = xs[c][lane];
        s1 += v * Wsrc[c * 4 + q];
        s2 += v * Wdst[c * 4 + q];
    }
    int n = n0 + lane;
    as_t[((size_t)q * N_ + n) * G_ + g] = s1;
    ad_t[((size_t)q * N_ + n) * G_ + g] = s2;

    #pragma unroll
    for (int i = 0; i < 16; ++i) {
        int nl = q + i * 4;
        xt[((size_t)(g * N_ + n0 + nl)) * 64 + lane] = xs[lane][nl];
    }
}

// ---------------- K3: edge softmax stats + unnormalized alpha -------------------
// block = node n; 384 threads, g-inner (coalesced as_t reads). No reductions:
// leaky is monotone -> max logit = leaky(max_s as + ad).
__global__ __launch_bounds__(384) void k_alpha(
    const float* __restrict__ as_t, const float* __restrict__ ad_t,
    const int* __restrict__ off, const int* __restrict__ srclist,
    float* __restrict__ alpha, float* __restrict__ sinv)
{
    int n   = blockIdx.x;
    int tid = threadIdx.x;
    int g   = tid % 96;                    // g inner: coalesced
    int hh  = tid / 96;
    int o0  = off[n], deg = off[n + 1] - o0;

    float advv = ad_t[((size_t)hh * N_ + n) * G_ + g];

    float Ms = -1e30f;
    for (int e = 0; e < deg; ++e) {
        int s = srclist[o0 + e];
        Ms = fmaxf(Ms, as_t[((size_t)hh * N_ + s) * G_ + g]);
    }
    float mraw = Ms + advv;
    float mx = mraw > 0.f ? mraw : 0.2f * mraw;

    float sm = 0.f;
    for (int e = 0; e < deg; ++e) {
        int s = srclist[o0 + e];
        float v = as_t[((size_t)hh * N_ + s) * G_ + g] + advv;
        v = v > 0.f ? v : 0.2f * v;
        float w = __expf(v - mx);
        sm += w;
        alpha[((size_t)g * EP_ + o0 + e) * H_ + hh] = w;
    }
    sinv[(size_t)(g * N_ + n) * H_ + hh] = 1.f / sm;
}

// ---------------- K4: fused aggregate (LDS z-tile) + GEMM + transpose-out -------
// block = (g, 32-node tile): 1536 blocks, XCD-swizzled, 256 threads.
// LDS: Bfr 32 KB + zt 33.3 KB -> 2 blocks/CU.
__global__ __launch_bounds__(256) void k_fused(
    const float* __restrict__ xt, const float* __restrict__ alpha,
    const float* __restrict__ sinv,
    const int* __restrict__ off, const int* __restrict__ srclist,
    const unsigned short* __restrict__ Wfrag, const float* __restrict__ bias,
    float* __restrict__ out)
{
    __shared__ unsigned short Bfr[8][4][64][8];   // 32 KB, [ks][nt][l][j]
    __shared__ float zt[32][260];                 // 33.3 KB (pad 260: phase-B banks)

    int bid  = blockIdx.x;                 // 1536 = 8 xcd * 12 g * 16 tiles
    int xcd  = bid & 7;
    int r    = bid >> 3;                   // 0..191
    int g    = xcd * 12 + (r >> 4);
    int tile = r & 15;
    int b    = g / T_, t = g - b * T_;
    int n0   = tile * 32;
    int tid  = threadIdx.x;
    int wave = tid >> 6, lane = tid & 63;

    // phase 0: Wfrag (pre-swizzled) -> LDS
    {
        const float4* src = reinterpret_cast<const float4*>(Wfrag);
        float4* dst = reinterpret_cast<float4*>(&Bfr[0][0][0][0]);
        #pragma unroll
        for (int it = 0; it < 8; ++it)
            dst[tid + it * 256] = src[tid + it * 256];
    }

    // phase A: aggregate z for 8 nodes per wave, 2 rounds of 4-node interleave
    #pragma unroll
    for (int round = 0; round < 2; ++round) {
        int nb = wave * 8 + round * 4;     // local node base
        int o0_[4], dg[4];
        #pragma unroll
        for (int u = 0; u < 4; ++u) {
            int n = n0 + nb + u;
            o0_[u] = off[n];
            dg[u]  = off[n + 1] - o0_[u];
        }
        int dmax = max(max(dg[0], dg[1]), max(dg[2], dg[3]));
        float ac[4][4];
        #pragma unroll
        for (int u = 0; u < 4; ++u)
            #pragma unroll
            for (int hh = 0; hh < 4; ++hh) ac[u][hh] = 0.f;

        for (int e = 0; e < dmax; ++e) {
            #pragma unroll
            for (int u = 0; u < 4; ++u) {
                if (e < dg[u]) {
                    int s = srclist[o0_[u] + e];
                    float xv = xt[((size_t)(g * N_ + s)) * 64 + lane];
                    float4 a = *reinterpret_cast<const float4*>(
                        &alpha[((size_t)g * EP_ + o0_[u] + e) * H_]);
                    ac[u][0] += a.x * xv;
                    ac[u][1] += a.y * xv;
                    ac[u][2] += a.z * xv;
                    ac[u][3] += a.w * xv;
                }
            }
        }
        #pragma unroll
        for (int u = 0; u < 4; ++u) {
            int n = n0 + nb + u;
            float4 inv = *reinterpret_cast<const float4*>(&sinv[(size_t)(g * N_ + n) * H_]);
            zt[nb + u][  0 + lane] = ac[u][0] * inv.x;
            zt[nb + u][ 64 + lane] = ac[u][1] * inv.y;
            zt[nb + u][128 + lane] = ac[u][2] * inv.z;
            zt[nb + u][192 + lane] = ac[u][3] * inv.w;
        }
    }
    __syncthreads();

    // phase B: out32x64 = zt(32x256) @ Wcat(256x64), 2-term split-bf16 MFMA
    int strip = wave & 1;                  // node half (rows)
    int ch    = wave >> 1;                 // col half
    int m = lane & 15, quad = lane >> 4;
    int row = strip * 16 + m;

    f32x4 acc2[2];
    acc2[0] = (f32x4){0.f, 0.f, 0.f, 0.f};
    acc2[1] = (f32x4){0.f, 0.f, 0.f, 0.f};

    #pragma unroll
    for (int ks = 0; ks < 8; ++ks) {
        float av[8];
        *reinterpret_cast<float4*>(&av[0]) =
            *reinterpret_cast<const float4*>(&zt[row][ks * 32 + quad * 8]);
        *reinterpret_cast<float4*>(&av[4]) =
            *reinterpret_cast<const float4*>(&zt[row][ks * 32 + quad * 8 + 4]);
        usx8 uhi, ulo;
        #pragma unroll
        for (int j = 0; j < 8; ++j) {
            unsigned short hi = f2bf(av[j]);
            uhi[j] = hi;
            ulo[j] = f2bf(av[j] - bf2f(hi));
        }
        bf16x8 zhi = __builtin_bit_cast(bf16x8, uhi);
        bf16x8 zlo = __builtin_bit_cast(bf16x8, ulo);
        #pragma unroll
        for (int nt2 = 0; nt2 < 2; ++nt2) {
            int nt = ch * 2 + nt2;
            bf16x8 bw = *reinterpret_cast<bf16x8*>(&Bfr[ks][nt][lane][0]);
            acc2[nt2] = __builtin_amdgcn_mfma_f32_16x16x32_bf16(zhi, bw, acc2[nt2], 0, 0, 0);
            acc2[nt2] = __builtin_amdgcn_mfma_f32_16x16x32_bf16(zlo, bw, acc2[nt2], 0, 0, 0);
        }
    }
    __syncthreads();   // zt reads done; reuse zt as transpose buffer

    float* tl = &zt[0][0];                 // tl[row][co] stride 65
    #pragma unroll
    for (int nt2 = 0; nt2 < 2; ++nt2) {
        int co = (ch * 2 + nt2) * 16 + m;  // D col = lane&15
        float bv = bias[co];
        #pragma unroll
        for (int rr = 0; rr < 4; ++rr) {
            int orow = strip * 16 + quad * 4 + rr;  // D row = quad*4+reg
            tl[orow * 65 + co] = 0.25f * acc2[nt2][rr] + bv;
        }
    }
    __syncthreads();

    // phase C: write out[b][co][t][n0..n0+32), lanes = n-inner (128B runs)
    int cbase = tid >> 5;                  // 0..7
    int nl    = tid & 31;
    #pragma unroll
    for (int i = 0; i < 8; ++i) {
        int co = cbase + i * 8;
        out[((size_t)(b * CO_ + co) * T_ + t) * N_ + n0 + nl] = tl[nl * 65 + co];
    }
}

extern "C" void kernel_launch(void* const* d_in, const int* in_sizes, int n_in,
                              void* d_out, int out_size, void* d_ws, size_t ws_size,
                              hipStream_t stream) {
    const float* x       = (const float*)d_in[0];
    const int*   ei      = (const int*)  d_in[1];
    const float* W       = (const float*)d_in[2];
    const float* att_src = (const float*)d_in[3];
    const float* att_dst = (const float*)d_in[4];
    const float* bias    = (const float*)d_in[5];
    float* out = (float*)d_out;

    char* p = (char*)d_ws;
    float* xt      = (float*)p;  p += (size_t)G_ * N_ * C_ * sizeof(float);       // 12.6 MB
    float* alpha   = (float*)p;  p += (size_t)G_ * EP_ * H_ * sizeof(float);      // 13.4 MB
    float* as_t    = (float*)p;  p += (size_t)H_ * N_ * G_ * sizeof(float);
    float* ad_t    = (float*)p;  p += (size_t)H_ * N_ * G_ * sizeof(float);
    float* sinv    = (float*)p;  p += (size_t)G_ * N_ * H_ * sizeof(float);
    float* Wsrc    = (float*)p;  p += C_ * H_ * sizeof(float);
    float* Wdst    = (float*)p;  p += C_ * H_ * sizeof(float);
    unsigned short* Wfrag = (unsigned short*)p; p += 64 * 256 * sizeof(unsigned short);
    int* off       = (int*)p;    p += 516 * sizeof(int);
    int* srclist   = (int*)p;    p += EP_ * sizeof(int);

    k_csr   <<<1,       512, 0, stream>>>(ei, W, att_src, att_dst, Wsrc, Wdst, off, srclist, Wfrag);
    k_prep  <<<G_ * 8,  256, 0, stream>>>(x, Wsrc, Wdst, xt, as_t, ad_t);
    k_alpha <<<N_,      384, 0, stream>>>(as_t, ad_t, off, srclist, alpha, sinv);
    k_fused <<<G_ * 16, 256, 0, stream>>>(xt, alpha, sinv, off, srclist, Wfrag, bias, out);
}

// Round 6
// 151.301 us; speedup vs baseline: 1.9256x; 1.9256x over previous
//
#include <hip/hip_runtime.h>

#define B_  8
#define C_  64
#define T_  12
#define N_  512
#define E_  8192
#define H_  4
#define CO_ 64
#define G_  (B_ * T_)        // 96
#define EP_ (E_ + N_)        // 8704 edges incl self loops
#define MAXDEG 128

typedef __bf16 bf16x8 __attribute__((ext_vector_type(8)));
typedef unsigned short usx8 __attribute__((ext_vector_type(8)));
typedef float  f32x4  __attribute__((ext_vector_type(4)));

static __device__ __forceinline__ unsigned short f2bf(float f) {
    unsigned int u = __float_as_uint(f);
    return (unsigned short)((u + 0x7fffu + ((u >> 16) & 1u)) >> 16);   // RNE
}

// ---------------- K1: Wsrc/Wdst reduction + CSR build + W-frag pre-swizzle ------
__global__ __launch_bounds__(512) void k_csr(
    const int* __restrict__ ei, const float* __restrict__ W,
    const float* __restrict__ att_src, const float* __restrict__ att_dst,
    float* __restrict__ Wsrc, float* __restrict__ Wdst,
    int* __restrict__ off, int* __restrict__ srclist,
    unsigned short* __restrict__ Wfrag)
{
    __shared__ int lcnt[512];
    __shared__ int lscan[512];
    int tid = threadIdx.x;

    if (tid < 256) {
        int c = tid & 63, hh = tid >> 6;
        float s1 = 0.f, s2 = 0.f;
        for (int co = 0; co < 64; ++co) {
            float w = W[c * 256 + hh * 64 + co];
            s1 += w * att_src[hh * 64 + co];
            s2 += w * att_dst[hh * 64 + co];
        }
        Wsrc[c * 4 + hh] = s1;
        Wdst[c * 4 + hh] = s2;
    }

    // W -> bf16 B-fragment layout for Wcat[k=h*64+c][co]
    for (int idx = tid; idx < 64 * 256; idx += 512) {
        int c  = idx >> 8, r = idx & 255;
        int hh = r >> 6,  co = r & 63;
        int k  = hh * 64 + c;
        int ks = k >> 5, kq = (k >> 3) & 3, j = k & 7;
        int nt = co >> 4, l = kq * 16 + (co & 15);
        Wfrag[(size_t)((ks * 4 + nt) * 64 + l) * 8 + j] = f2bf(W[idx]);
    }

    lcnt[tid] = 1;                        // self loop
    __syncthreads();
    for (int e = tid; e < E_; e += 512)
        atomicAdd(&lcnt[ei[E_ + e]], 1);
    __syncthreads();
    int v = lcnt[tid];
    lscan[tid] = v;
    __syncthreads();
    for (int d = 1; d < 512; d <<= 1) {
        int val = (tid >= d) ? lscan[tid - d] : 0;
        __syncthreads();
        lscan[tid] += val;
        __syncthreads();
    }
    int excl = lscan[tid] - v;
    off[tid] = excl;
    if (tid == 511) off[512] = lscan[511];
    lcnt[tid] = excl;                     // cursor
    __syncthreads();
    for (int e = tid; e < EP_; e += 512) {
        int d, s;
        if (e < E_) { d = ei[E_ + e]; s = ei[e]; }
        else        { d = e - E_;     s = d; }
        int pos = atomicAdd(&lcnt[d], 1);
        srclist[pos] = s;
    }
}

// ---------------- K2: xt transpose + as_t/ad_t logit dots ([h][n][g] layout) ----
__global__ __launch_bounds__(256) void k_prep(
    const float* __restrict__ x, const float* __restrict__ Wsrc,
    const float* __restrict__ Wdst,
    float* __restrict__ xt, float* __restrict__ as_t, float* __restrict__ ad_t)
{
    __shared__ float xs[64][65];
    int bid  = blockIdx.x;                 // 768 = 8 xcd * 12 g * 8 tiles
    int xcd  = bid & 7;
    int r    = bid >> 3;
    int g    = xcd * 12 + (r >> 3);
    int tile = r & 7;
    int b    = g / T_, t = g - b * T_;
    int n0   = tile * 64;
    int tid  = threadIdx.x;
    int lane = tid & 63, q = tid >> 6;

    #pragma unroll
    for (int i = 0; i < 16; ++i) {
        int c = q + i * 4;
        xs[c][lane] = x[((size_t)(b * C_ + c) * T_ + t) * N_ + n0 + lane];
    }
    __syncthreads();

    float s1 = 0.f, s2 = 0.f;
    for (int c = 0; c < 64; ++c) {
        float v = xs[c][lane];
        s1 += v * Wsrc[c * 4 + q];
        s2 += v * Wdst[c * 4 + q];
    }
    int n = n0 + lane;
    as_t[((size_t)q * N_ + n) * G_ + g] = s1;
    ad_t[((size_t)q * N_ + n) * G_ + g] = s2;

    #pragma unroll
    for (int i = 0; i < 16; ++i) {
        int nl = q + i * 4;
        xt[((size_t)(g * N_ + n0 + nl)) * 64 + lane] = xs[lane][nl];
    }
}

// ---------------- K3: edge softmax, block=n, threads=(g inner, h outer) --------
// Fully coalesced: as_t reads 384B runs, alpha3 [e][h][g] writes 384B runs.
__global__ __launch_bounds__(384) void k_alpha(
    const float* __restrict__ as_t, const float* __restrict__ ad_t,
    const int* __restrict__ off, const int* __restrict__ srclist,
    float* __restrict__ alpha3, float* __restrict__ sinv2)
{
    __shared__ int ls[MAXDEG];
    int n   = blockIdx.x;
    int tid = threadIdx.x;
    int o0  = off[n], deg = off[n + 1] - o0;
    for (int e = tid; e < deg; e += 384) ls[e] = srclist[o0 + e];
    __syncthreads();

    int g  = tid % 96;
    int hh = tid / 96;
    const float* asb = as_t + (size_t)hh * N_ * G_ + g;
    float advv = ad_t[((size_t)hh * N_ + n) * G_ + g];

    float Ms = -1e30f;
    int e = 0;
    for (; e + 4 <= deg; e += 4) {
        float a0 = asb[(size_t)ls[e+0] * G_];
        float a1 = asb[(size_t)ls[e+1] * G_];
        float a2 = asb[(size_t)ls[e+2] * G_];
        float a3 = asb[(size_t)ls[e+3] * G_];
        Ms = fmaxf(Ms, fmaxf(fmaxf(a0, a1), fmaxf(a2, a3)));
    }
    for (; e < deg; ++e) Ms = fmaxf(Ms, asb[(size_t)ls[e] * G_]);
    float mraw = Ms + advv;
    float mx = mraw > 0.f ? mraw : 0.2f * mraw;   // leaky monotone

    float sm = 0.f;
    for (e = 0; e < deg; ++e) {
        float v = asb[(size_t)ls[e] * G_] + advv;
        v = v > 0.f ? v : 0.2f * v;
        float w = __expf(v - mx);
        sm += w;
        alpha3[((size_t)(o0 + e) * H_ + hh) * G_ + g] = w;
    }
    sinv2[((size_t)n * H_ + hh) * G_ + g] = 1.f / sm;
}

// ---------------- K4: aggregate z[g,n,h,:] = sum_e alpha*xt[src] -> bf16 -------
// block = (xcd, g-quad, n): 4 waves share node n across 4 consecutive g.
// srclist staged once; alpha staged cooperatively; edge loop unrolled x8.
__global__ __launch_bounds__(256) void k_aggr(
    const float* __restrict__ xt, const float* __restrict__ alpha3,
    const float* __restrict__ sinv2,
    const int* __restrict__ off, const int* __restrict__ srclist,
    unsigned short* __restrict__ zb)
{
    __shared__ float wbuf[MAXDEG][4][4];   // [e][gl][h], 8 KB
    __shared__ int   ssrc[MAXDEG];
    int tid  = threadIdx.x;
    int wave = tid >> 6, lane = tid & 63;
    int xcd  = blockIdx.x & 7;
    int slot = blockIdx.x >> 3;            // 0..1535
    int n    = slot & 511;
    int gq   = slot >> 9;                  // 0..2
    int g0   = xcd * 12 + gq * 4;
    int o0   = off[n], deg = off[n + 1] - o0;

    // cooperative staging: 16 threads per edge -> (gl,h)
    int sub = tid & 15, gl = sub & 3, hh = sub >> 2;
    float sv = sinv2[((size_t)n * H_ + hh) * G_ + g0 + gl];
    for (int e = tid >> 4; e < deg; e += 16)
        wbuf[e][gl][hh] = alpha3[((size_t)(o0 + e) * H_ + hh) * G_ + g0 + gl] * sv;
    for (int e = tid; e < deg; e += 256)
        ssrc[e] = srclist[o0 + e];
    __syncthreads();

    int g = g0 + wave;
    const float* xg = xt + (size_t)g * N_ * 64 + lane;
    float z0 = 0.f, z1 = 0.f, z2 = 0.f, z3 = 0.f;
    int e = 0;
    for (; e + 8 <= deg; e += 8) {
        float xv[8];
        #pragma unroll
        for (int u = 0; u < 8; ++u) xv[u] = xg[(size_t)ssrc[e + u] * 64];
        #pragma unroll
        for (int u = 0; u < 8; ++u) {
            float4 w = *reinterpret_cast<const float4*>(&wbuf[e + u][wave][0]);
            z0 += w.x * xv[u];
            z1 += w.y * xv[u];
            z2 += w.z * xv[u];
            z3 += w.w * xv[u];
        }
    }
    for (; e < deg; ++e) {
        float xv = xg[(size_t)ssrc[e] * 64];
        float4 w = *reinterpret_cast<const float4*>(&wbuf[e][wave][0]);
        z0 += w.x * xv;
        z1 += w.y * xv;
        z2 += w.z * xv;
        z3 += w.w * xv;
    }
    size_t base = ((size_t)g * N_ + n) * 256 + lane;
    zb[base +   0] = f2bf(z0);
    zb[base +  64] = f2bf(z1);
    zb[base + 128] = f2bf(z2);
    zb[base + 192] = f2bf(z3);
}

// ---------------- K5: out = 0.25*zb@Wcat + bias, fused transpose ---------------
__global__ __launch_bounds__(256) void k_out(
    const unsigned short* __restrict__ zb, const unsigned short* __restrict__ Wfrag,
    const float* __restrict__ bias, float* __restrict__ out)
{
    __shared__ char lds[32768];
    unsigned short (*Bfr)[4][64][8] = (unsigned short (*)[4][64][8])lds;   // 32 KB
    float (*tl)[65] = (float (*)[65])lds;   // alias after MFMA barrier (16.6 KB)

    int bid  = blockIdx.x;                 // 768
    int xcd  = bid & 7;
    int r    = bid >> 3;
    int g    = xcd * 12 + (r >> 3);
    int tile = r & 7;
    int b    = g / T_, t = g - b * T_;
    int n0   = tile * 64;
    int tid  = threadIdx.x;

    {
        const float4* src = reinterpret_cast<const float4*>(Wfrag);
        float4* dst = reinterpret_cast<float4*>(&Bfr[0][0][0][0]);
        #pragma unroll
        for (int it = 0; it < 8; ++it)
            dst[tid + it * 256] = src[tid + it * 256];
    }
    __syncthreads();

    int i = tid >> 6, l = tid & 63;
    int m = l & 15, quad = l >> 4;
    const unsigned short* zrow = zb + ((size_t)(g * N_) + n0 + i * 16 + m) * 256 + quad * 8;

    f32x4 acc[4];
    #pragma unroll
    for (int nt = 0; nt < 4; ++nt) acc[nt] = (f32x4){0.f, 0.f, 0.f, 0.f};

    #pragma unroll
    for (int ks = 0; ks < 8; ++ks) {
        usx8 ua = *reinterpret_cast<const usx8*>(zrow + ks * 32);
        bf16x8 a = __builtin_bit_cast(bf16x8, ua);
        #pragma unroll
        for (int nt = 0; nt < 4; ++nt) {
            bf16x8 bw = *reinterpret_cast<bf16x8*>(&Bfr[ks][nt][l][0]);
            acc[nt] = __builtin_amdgcn_mfma_f32_16x16x32_bf16(a, bw, acc[nt], 0, 0, 0);
        }
    }
    __syncthreads();   // Bfr reads done; safe to alias tl

    #pragma unroll
    for (int nt = 0; nt < 4; ++nt) {
        int co = nt * 16 + m;               // D col = lane&15
        float bv = bias[co];
        #pragma unroll
        for (int rr = 0; rr < 4; ++rr) {
            int row = i * 16 + quad * 4 + rr; // D row = quad*4+reg
            tl[row][co] = 0.25f * acc[nt][rr] + bv;
        }
    }
    __syncthreads();

    #pragma unroll
    for (int it = 0; it < 16; ++it) {
        int c = i + it * 4;
        out[((size_t)(b * CO_ + c) * T_ + t) * N_ + n0 + l] = tl[l][c];
    }
}

extern "C" void kernel_launch(void* const* d_in, const int* in_sizes, int n_in,
                              void* d_out, int out_size, void* d_ws, size_t ws_size,
                              hipStream_t stream) {
    const float* x       = (const float*)d_in[0];
    const int*   ei      = (const int*)  d_in[1];
    const float* W       = (const float*)d_in[2];
    const float* att_src = (const float*)d_in[3];
    const float* att_dst = (const float*)d_in[4];
    const float* bias    = (const float*)d_in[5];
    float* out = (float*)d_out;

    char* p = (char*)d_ws;
    float* xt      = (float*)p;  p += (size_t)G_ * N_ * C_ * sizeof(float);        // 12.6 MB
    float* alpha3  = (float*)p;  p += (size_t)EP_ * H_ * G_ * sizeof(float);       // 13.4 MB
    unsigned short* zb = (unsigned short*)p; p += (size_t)G_ * N_ * 256 * sizeof(unsigned short); // 25.2 MB
    float* as_t    = (float*)p;  p += (size_t)H_ * N_ * G_ * sizeof(float);
    float* ad_t    = (float*)p;  p += (size_t)H_ * N_ * G_ * sizeof(float);
    float* sinv2   = (float*)p;  p += (size_t)N_ * H_ * G_ * sizeof(float);
    float* Wsrc    = (float*)p;  p += C_ * H_ * sizeof(float);
    float* Wdst    = (float*)p;  p += C_ * H_ * sizeof(float);
    unsigned short* Wfrag = (unsigned short*)p; p += 64 * 256 * sizeof(unsigned short);
    int* off       = (int*)p;    p += 516 * sizeof(int);
    int* srclist   = (int*)p;    p += EP_ * sizeof(int);

    k_csr   <<<1,        512, 0, stream>>>(ei, W, att_src, att_dst, Wsrc, Wdst, off, srclist, Wfrag);
    k_prep  <<<G_ * 8,   256, 0, stream>>>(x, Wsrc, Wdst, xt, as_t, ad_t);
    k_alpha <<<N_,       384, 0, stream>>>(as_t, ad_t, off, srclist, alpha3, sinv2);
    k_aggr  <<<8 * 1536, 256, 0, stream>>>(xt, alpha3, sinv2, off, srclist, zb);
    k_out   <<<G_ * 8,   256, 0, stream>>>(zb, Wfrag, bias, out);
}

// Round 7
// 135.881 us; speedup vs baseline: 2.1441x; 1.1135x over previous
//
#include <hip/hip_runtime.h>

#define B_  8
#define C_  64
#define T_  12
#define N_  512
#define E_  8192
#define H_  4
#define CO_ 64
#define G_  (B_ * T_)        // 96
#define EP_ (E_ + N_)        // 8704 edges incl self loops
#define MAXDEG 128

typedef __bf16 bf16x8 __attribute__((ext_vector_type(8)));
typedef unsigned short usx8 __attribute__((ext_vector_type(8)));
typedef float  f32x4  __attribute__((ext_vector_type(4)));

static __device__ __forceinline__ unsigned short f2bf(float f) {
    unsigned int u = __float_as_uint(f);
    return (unsigned short)((u + 0x7fffu + ((u >> 16) & 1u)) >> 16);   // RNE
}

// ---------------- K1: prep (blocks 0..383) + CSR/Wfrag (block 384) -------------
// prep block: two 64-node tiles; Wsrc/Wdst computed in-block (no dependency).
__global__ __launch_bounds__(512) void k_prep(
    const float* __restrict__ x, const int* __restrict__ ei,
    const float* __restrict__ W,
    const float* __restrict__ att_src, const float* __restrict__ att_dst,
    float* __restrict__ xt, float* __restrict__ as_t, float* __restrict__ ad_t,
    int* __restrict__ off, int* __restrict__ srclist,
    unsigned short* __restrict__ Wfrag)
{
    int tid = threadIdx.x;

    if (blockIdx.x == 384) {
        // ---- CSR build + Wfrag pre-swizzle ----
        __shared__ int lcnt[512];
        __shared__ int lscan[512];

        for (int idx = tid; idx < 64 * 256; idx += 512) {
            int c  = idx >> 8, r = idx & 255;
            int hh = r >> 6,  co = r & 63;
            int k  = hh * 64 + c;
            int ks = k >> 5, kq = (k >> 3) & 3, j = k & 7;
            int nt = co >> 4, l = kq * 16 + (co & 15);
            Wfrag[(size_t)((ks * 4 + nt) * 64 + l) * 8 + j] = f2bf(W[idx]);
        }

        lcnt[tid] = 1;                        // self loop
        __syncthreads();
        for (int e = tid; e < E_; e += 512)
            atomicAdd(&lcnt[ei[E_ + e]], 1);
        __syncthreads();
        int v = lcnt[tid];
        lscan[tid] = v;
        __syncthreads();
        for (int d = 1; d < 512; d <<= 1) {
            int val = (tid >= d) ? lscan[tid - d] : 0;
            __syncthreads();
            lscan[tid] += val;
            __syncthreads();
        }
        int excl = lscan[tid] - v;
        off[tid] = excl;
        if (tid == 511) off[512] = lscan[511];
        lcnt[tid] = excl;                     // cursor
        __syncthreads();
        for (int e = tid; e < EP_; e += 512) {
            int d, s;
            if (e < E_) { d = ei[E_ + e]; s = ei[e]; }
            else        { d = e - E_;     s = d; }
            int pos = atomicAdd(&lcnt[d], 1);
            srclist[pos] = s;
        }
        return;
    }

    // ---- prep path: two tiles per block ----
    __shared__ float xs[2][64][65];           // 33.3 KB
    __shared__ float Wls[64][4], Wld[64][4];  // 2 KB

    if (tid < 256) {                          // redundant Wsrc/Wdst (L2-hot W)
        int c = tid & 63, hh = tid >> 6;
        float s1 = 0.f, s2 = 0.f;
        for (int co = 0; co < 64; ++co) {
            float w = W[c * 256 + hh * 64 + co];
            s1 += w * att_src[hh * 64 + co];
            s2 += w * att_dst[hh * 64 + co];
        }
        Wls[c][hh] = s1;
        Wld[c][hh] = s2;
    }

    int half = tid >> 8;                      // which tile
    int t256 = tid & 255;
    int lane = t256 & 63, q = t256 >> 6;
    int tile_id = blockIdx.x * 2 + half;      // 0..767
    int g  = tile_id >> 3, tl = tile_id & 7;
    int b  = g / T_, t = g - b * T_;
    int n0 = tl * 64;

    #pragma unroll
    for (int i = 0; i < 16; ++i) {
        int c = q + i * 4;
        xs[half][c][lane] = x[((size_t)(b * C_ + c) * T_ + t) * N_ + n0 + lane];
    }
    __syncthreads();

    float s1 = 0.f, s2 = 0.f;
    for (int c = 0; c < 64; ++c) {
        float v = xs[half][c][lane];
        s1 += v * Wls[c][q];
        s2 += v * Wld[c][q];
    }
    int n = n0 + lane;
    as_t[((size_t)q * N_ + n) * G_ + g] = s1;
    ad_t[((size_t)q * N_ + n) * G_ + g] = s2;

    #pragma unroll
    for (int i = 0; i < 16; ++i) {
        int nl = q + i * 4;
        xt[((size_t)(g * N_ + n0 + nl)) * 64 + lane] = xs[half][lane][nl];
    }
}

// ---------------- K2: fused softmax + aggregate -> zb (bf16) -------------------
// block = (xcd, g-quad, n). Softmax in-block: 16 threads per (g,h) pair,
// LDS tree reductions; alphas never touch global.
__global__ __launch_bounds__(256) void k_aggr(
    const float* __restrict__ xt, const float* __restrict__ as_t,
    const float* __restrict__ ad_t,
    const int* __restrict__ off, const int* __restrict__ srclist,
    unsigned short* __restrict__ zb)
{
    __shared__ float awk[MAXDEG][16];      // raw a_src gathers, 8 KB
    __shared__ float wbuf[MAXDEG][4][4];   // normalized alpha [e][gl][hh], 8 KB
    __shared__ float red[16][17];          // reduction scratch
    __shared__ int   ssrc[MAXDEG];
    int tid  = threadIdx.x;
    int wave = tid >> 6, lane = tid & 63;
    int xcd  = blockIdx.x & 7;
    int slot = blockIdx.x >> 3;            // 0..1535
    int n    = slot & 511;
    int gq   = slot >> 9;                  // 0..2
    int g0   = xcd * 12 + gq * 4;
    int o0   = off[n], deg = off[n + 1] - o0;

    for (int e = tid; e < deg; e += 256)
        ssrc[e] = srclist[o0 + e];
    __syncthreads();

    // softmax: sub=(hh,gl) pair, p strides edges
    int sub = tid & 15, p = tid >> 4;
    int hh = sub >> 2, gl = sub & 3;
    int gg = g0 + gl;
    float adv = ad_t[((size_t)hh * N_ + n) * G_ + gg];

    float Ms = -1e30f;
    for (int e = p; e < deg; e += 16) {
        float a = as_t[((size_t)hh * N_ + ssrc[e]) * G_ + gg];
        awk[e][sub] = a;
        Ms = fmaxf(Ms, a);
    }
    red[sub][p] = Ms;
    __syncthreads();
    #pragma unroll
    for (int d = 8; d; d >>= 1) {
        if (p < d) red[sub][p] = fmaxf(red[sub][p], red[sub][p + d]);
        __syncthreads();
    }
    float mraw = red[sub][0] + adv;
    float mx = mraw > 0.f ? mraw : 0.2f * mraw;   // leaky monotone
    __syncthreads();

    float sp = 0.f;
    for (int e = p; e < deg; e += 16) {
        float v = awk[e][sub] + adv;
        v = v > 0.f ? v : 0.2f * v;
        sp += __expf(v - mx);
    }
    red[sub][p] = sp;
    __syncthreads();
    #pragma unroll
    for (int d = 8; d; d >>= 1) {
        if (p < d) red[sub][p] += red[sub][p + d];
        __syncthreads();
    }
    float inv = 1.f / red[sub][0];
    for (int e = p; e < deg; e += 16) {
        float v = awk[e][sub] + adv;
        v = v > 0.f ? v : 0.2f * v;
        wbuf[e][gl][hh] = __expf(v - mx) * inv;
    }
    __syncthreads();

    // gather phase: wave = local graph, lane = channel
    int g = g0 + wave;
    const float* xg = xt + (size_t)g * N_ * 64 + lane;
    float z0 = 0.f, z1 = 0.f, z2 = 0.f, z3 = 0.f;
    int e = 0;
    for (; e + 8 <= deg; e += 8) {
        float xv[8];
        #pragma unroll
        for (int u = 0; u < 8; ++u) xv[u] = xg[(size_t)ssrc[e + u] * 64];
        #pragma unroll
        for (int u = 0; u < 8; ++u) {
            float4 w = *reinterpret_cast<const float4*>(&wbuf[e + u][wave][0]);
            z0 += w.x * xv[u];
            z1 += w.y * xv[u];
            z2 += w.z * xv[u];
            z3 += w.w * xv[u];
        }
    }
    for (; e < deg; ++e) {
        float xv = xg[(size_t)ssrc[e] * 64];
        float4 w = *reinterpret_cast<const float4*>(&wbuf[e][wave][0]);
        z0 += w.x * xv;
        z1 += w.y * xv;
        z2 += w.z * xv;
        z3 += w.w * xv;
    }
    size_t base = ((size_t)g * N_ + n) * 256 + lane;
    zb[base +   0] = f2bf(z0);
    zb[base +  64] = f2bf(z1);
    zb[base + 128] = f2bf(z2);
    zb[base + 192] = f2bf(z3);
}

// ---------------- K3: out = 0.25*zb@Wcat + bias, fused transpose ---------------
__global__ __launch_bounds__(256) void k_out(
    const unsigned short* __restrict__ zb, const unsigned short* __restrict__ Wfrag,
    const float* __restrict__ bias, float* __restrict__ out)
{
    __shared__ char lds[32768];
    unsigned short (*Bfr)[4][64][8] = (unsigned short (*)[4][64][8])lds;   // 32 KB
    float (*tl)[65] = (float (*)[65])lds;   // alias after MFMA barrier

    int bid  = blockIdx.x;                 // 768
    int xcd  = bid & 7;
    int r    = bid >> 3;
    int g    = xcd * 12 + (r >> 3);
    int tile = r & 7;
    int b    = g / T_, t = g - b * T_;
    int n0   = tile * 64;
    int tid  = threadIdx.x;

    {
        const float4* src = reinterpret_cast<const float4*>(Wfrag);
        float4* dst = reinterpret_cast<float4*>(&Bfr[0][0][0][0]);
        #pragma unroll
        for (int it = 0; it < 8; ++it)
            dst[tid + it * 256] = src[tid + it * 256];
    }
    __syncthreads();

    int i = tid >> 6, l = tid & 63;
    int m = l & 15, quad = l >> 4;
    const unsigned short* zrow = zb + ((size_t)(g * N_) + n0 + i * 16 + m) * 256 + quad * 8;

    f32x4 acc[4];
    #pragma unroll
    for (int nt = 0; nt < 4; ++nt) acc[nt] = (f32x4){0.f, 0.f, 0.f, 0.f};

    #pragma unroll
    for (int ks = 0; ks < 8; ++ks) {
        usx8 ua = *reinterpret_cast<const usx8*>(zrow + ks * 32);
        bf16x8 a = __builtin_bit_cast(bf16x8, ua);
        #pragma unroll
        for (int nt = 0; nt < 4; ++nt) {
            bf16x8 bw = *reinterpret_cast<bf16x8*>(&Bfr[ks][nt][l][0]);
            acc[nt] = __builtin_amdgcn_mfma_f32_16x16x32_bf16(a, bw, acc[nt], 0, 0, 0);
        }
    }
    __syncthreads();   // Bfr reads done; safe to alias tl

    #pragma unroll
    for (int nt = 0; nt < 4; ++nt) {
        int co = nt * 16 + m;               // D col = lane&15
        float bv = bias[co];
        #pragma unroll
        for (int rr = 0; rr < 4; ++rr) {
            int row = i * 16 + quad * 4 + rr; // D row = quad*4+reg
            tl[row][co] = 0.25f * acc[nt][rr] + bv;
        }
    }
    __syncthreads();

    #pragma unroll
    for (int it = 0; it < 16; ++it) {
        int c = i + it * 4;
        out[((size_t)(b * CO_ + c) * T_ + t) * N_ + n0 + l] = tl[l][c];
    }
}

extern "C" void kernel_launch(void* const* d_in, const int* in_sizes, int n_in,
                              void* d_out, int out_size, void* d_ws, size_t ws_size,
                              hipStream_t stream) {
    const float* x       = (const float*)d_in[0];
    const int*   ei      = (const int*)  d_in[1];
    const float* W       = (const float*)d_in[2];
    const float* att_src = (const float*)d_in[3];
    const float* att_dst = (const float*)d_in[4];
    const float* bias    = (const float*)d_in[5];
    float* out = (float*)d_out;

    char* p = (char*)d_ws;
    float* xt      = (float*)p;  p += (size_t)G_ * N_ * C_ * sizeof(float);        // 12.6 MB
    unsigned short* zb = (unsigned short*)p; p += (size_t)G_ * N_ * 256 * sizeof(unsigned short); // 25.2 MB
    float* as_t    = (float*)p;  p += (size_t)H_ * N_ * G_ * sizeof(float);
    float* ad_t    = (float*)p;  p += (size_t)H_ * N_ * G_ * sizeof(float);
    unsigned short* Wfrag = (unsigned short*)p; p += 64 * 256 * sizeof(unsigned short);
    int* off       = (int*)p;    p += 516 * sizeof(int);
    int* srclist   = (int*)p;    p += EP_ * sizeof(int);

    k_prep  <<<385,      512, 0, stream>>>(x, ei, W, att_src, att_dst,
                                           xt, as_t, ad_t, off, srclist, Wfrag);
    k_aggr  <<<8 * 1536, 256, 0, stream>>>(xt, as_t, ad_t, off, srclist, zb);
    k_out   <<<G_ * 8,   256, 0, stream>>>(zb, Wfrag, bias, out);
}

// Round 8
// 131.403 us; speedup vs baseline: 2.2172x; 1.0341x over previous
//
#include <hip/hip_runtime.h>

#define B_  8
#define C_  64
#define T_  12
#define N_  512
#define E_  8192
#define H_  4
#define CO_ 64
#define G_  (B_ * T_)        // 96
#define EP_ (E_ + N_)        // 8704 edges incl self loops
#define MAXDEG 128

typedef __bf16 bf16x8 __attribute__((ext_vector_type(8)));
typedef unsigned short usx8 __attribute__((ext_vector_type(8)));
typedef float  f32x4  __attribute__((ext_vector_type(4)));

static __device__ __forceinline__ unsigned short f2bf(float f) {
    unsigned int u = __float_as_uint(f);
    return (unsigned short)((u + 0x7fffu + ((u >> 16) & 1u)) >> 16);   // RNE
}

// ---------------- K1: prep (blocks 0..383) + CSR/Wfrag (block 384) -------------
__global__ __launch_bounds__(512) void k_prep(
    const float* __restrict__ x, const int* __restrict__ ei,
    const float* __restrict__ W,
    const float* __restrict__ att_src, const float* __restrict__ att_dst,
    float* __restrict__ xt, float* __restrict__ as_t, float* __restrict__ ad_t,
    int* __restrict__ off, int* __restrict__ srclist,
    unsigned short* __restrict__ Wfrag)
{
    int tid = threadIdx.x;

    if (blockIdx.x == 384) {
        __shared__ int lcnt[512];
        __shared__ int lscan[512];

        for (int idx = tid; idx < 64 * 256; idx += 512) {
            int c  = idx >> 8, r = idx & 255;
            int hh = r >> 6,  co = r & 63;
            int k  = hh * 64 + c;
            int ks = k >> 5, kq = (k >> 3) & 3, j = k & 7;
            int nt = co >> 4, l = kq * 16 + (co & 15);
            Wfrag[(size_t)((ks * 4 + nt) * 64 + l) * 8 + j] = f2bf(W[idx]);
        }

        lcnt[tid] = 1;                        // self loop
        __syncthreads();
        for (int e = tid; e < E_; e += 512)
            atomicAdd(&lcnt[ei[E_ + e]], 1);
        __syncthreads();
        int v = lcnt[tid];
        lscan[tid] = v;
        __syncthreads();
        for (int d = 1; d < 512; d <<= 1) {
            int val = (tid >= d) ? lscan[tid - d] : 0;
            __syncthreads();
            lscan[tid] += val;
            __syncthreads();
        }
        int excl = lscan[tid] - v;
        off[tid] = excl;
        if (tid == 511) off[512] = lscan[511];
        lcnt[tid] = excl;                     // cursor
        __syncthreads();
        for (int e = tid; e < EP_; e += 512) {
            int d, s;
            if (e < E_) { d = ei[E_ + e]; s = ei[e]; }
            else        { d = e - E_;     s = d; }
            int pos = atomicAdd(&lcnt[d], 1);
            srclist[pos] = s;
        }
        return;
    }

    __shared__ float xs[2][64][65];           // 33.3 KB
    __shared__ float Wls[64][4], Wld[64][4];  // 2 KB

    if (tid < 256) {                          // redundant Wsrc/Wdst (L2-hot W)
        int c = tid & 63, hh = tid >> 6;
        float s1 = 0.f, s2 = 0.f;
        for (int co = 0; co < 64; ++co) {
            float w = W[c * 256 + hh * 64 + co];
            s1 += w * att_src[hh * 64 + co];
            s2 += w * att_dst[hh * 64 + co];
        }
        Wls[c][hh] = s1;
        Wld[c][hh] = s2;
    }

    int half = tid >> 8;
    int t256 = tid & 255;
    int lane = t256 & 63, q = t256 >> 6;
    int tile_id = blockIdx.x * 2 + half;      // 0..767
    int g  = tile_id >> 3, tl = tile_id & 7;
    int b  = g / T_, t = g - b * T_;
    int n0 = tl * 64;

    #pragma unroll
    for (int i = 0; i < 16; ++i) {
        int c = q + i * 4;
        xs[half][c][lane] = x[((size_t)(b * C_ + c) * T_ + t) * N_ + n0 + lane];
    }
    __syncthreads();

    float s1 = 0.f, s2 = 0.f;
    for (int c = 0; c < 64; ++c) {
        float v = xs[half][c][lane];
        s1 += v * Wls[c][q];
        s2 += v * Wld[c][q];
    }
    int n = n0 + lane;
    as_t[((size_t)q * N_ + n) * G_ + g] = s1;
    ad_t[((size_t)q * N_ + n) * G_ + g] = s2;

    #pragma unroll
    for (int i = 0; i < 16; ++i) {
        int nl = q + i * 4;
        xt[((size_t)(g * N_ + n0 + nl)) * 64 + lane] = xs[half][lane][nl];
    }
}

// ---------------- K2: fused softmax + aggregate -> zb (bf16) -------------------
// block = (xcd, g-quad, n). No max-shift (|logit|<~8: exp safe in fp32),
// softmax denominator folded into the gather loop -> ONE barrier, no reductions.
__global__ __launch_bounds__(256) void k_aggr(
    const float* __restrict__ xt, const float* __restrict__ as_t,
    const float* __restrict__ ad_t,
    const int* __restrict__ off, const int* __restrict__ srclist,
    unsigned short* __restrict__ zb)
{
    __shared__ float wbuf[MAXDEG][4][4];   // unnormalized alpha [e][gl][hh], 8 KB
    __shared__ int   ssrc[MAXDEG];
    int tid  = threadIdx.x;
    int wave = tid >> 6, lane = tid & 63;
    int xcd  = blockIdx.x & 7;
    int slot = blockIdx.x >> 3;            // 0..1535
    int n    = slot & 511;
    int gq   = slot >> 9;                  // 0..2
    int g0   = xcd * 12 + gq * 4;
    int o0   = off[n], deg = off[n + 1] - o0;

    if (tid < deg) ssrc[tid] = srclist[o0 + tid];

    // fill wbuf: sub=(hh,gl) pair, p strides edges (srclist read is broadcast)
    int sub = tid & 15, p = tid >> 4;
    int hh = sub >> 2, gl = sub & 3;
    int gg = g0 + gl;
    float adv = ad_t[((size_t)hh * N_ + n) * G_ + gg];
    for (int e = p; e < deg; e += 16) {
        int s = srclist[o0 + e];
        float v = as_t[((size_t)hh * N_ + s) * G_ + gg] + adv;
        v = v > 0.f ? v : 0.2f * v;        // leaky relu
        wbuf[e][gl][hh] = __expf(v);       // no max-shift needed (bounded logits)
    }
    __syncthreads();

    // gather: wave = local graph, lane = channel; denominator accumulated inline
    int g = g0 + wave;
    const float* xg = xt + (size_t)g * N_ * 64 + lane;
    float z0 = 0.f, z1 = 0.f, z2 = 0.f, z3 = 0.f;
    float s0 = 0.f, s1 = 0.f, s2 = 0.f, s3 = 0.f;
    int e = 0;
    for (; e + 8 <= deg; e += 8) {
        float xv[8];
        #pragma unroll
        for (int u = 0; u < 8; ++u) xv[u] = xg[(size_t)ssrc[e + u] * 64];
        #pragma unroll
        for (int u = 0; u < 8; ++u) {
            float4 w = *reinterpret_cast<const float4*>(&wbuf[e + u][wave][0]);
            z0 += w.x * xv[u];  s0 += w.x;
            z1 += w.y * xv[u];  s1 += w.y;
            z2 += w.z * xv[u];  s2 += w.z;
            z3 += w.w * xv[u];  s3 += w.w;
        }
    }
    for (; e < deg; ++e) {
        float xv = xg[(size_t)ssrc[e] * 64];
        float4 w = *reinterpret_cast<const float4*>(&wbuf[e][wave][0]);
        z0 += w.x * xv;  s0 += w.x;
        z1 += w.y * xv;  s1 += w.y;
        z2 += w.z * xv;  s2 += w.z;
        z3 += w.w * xv;  s3 += w.w;
    }
    size_t base = ((size_t)g * N_ + n) * 256 + lane;
    zb[base +   0] = f2bf(z0 / s0);
    zb[base +  64] = f2bf(z1 / s1);
    zb[base + 128] = f2bf(z2 / s2);
    zb[base + 192] = f2bf(z3 / s3);
}

// ---------------- K3: out = 0.25*zb@Wcat + bias, fused transpose ---------------
__global__ __launch_bounds__(256) void k_out(
    const unsigned short* __restrict__ zb, const unsigned short* __restrict__ Wfrag,
    const float* __restrict__ bias, float* __restrict__ out)
{
    __shared__ char lds[32768];
    unsigned short (*Bfr)[4][64][8] = (unsigned short (*)[4][64][8])lds;   // 32 KB
    float (*tl)[65] = (float (*)[65])lds;   // alias after MFMA barrier

    int bid  = blockIdx.x;                 // 768
    int xcd  = bid & 7;
    int r    = bid >> 3;
    int g    = xcd * 12 + (r >> 3);
    int tile = r & 7;
    int b    = g / T_, t = g - b * T_;
    int n0   = tile * 64;
    int tid  = threadIdx.x;

    {
        const float4* src = reinterpret_cast<const float4*>(Wfrag);
        float4* dst = reinterpret_cast<float4*>(&Bfr[0][0][0][0]);
        #pragma unroll
        for (int it = 0; it < 8; ++it)
            dst[tid + it * 256] = src[tid + it * 256];
    }
    __syncthreads();

    int i = tid >> 6, l = tid & 63;
    int m = l & 15, quad = l >> 4;
    const unsigned short* zrow = zb + ((size_t)(g * N_) + n0 + i * 16 + m) * 256 + quad * 8;

    f32x4 acc[4];
    #pragma unroll
    for (int nt = 0; nt < 4; ++nt) acc[nt] = (f32x4){0.f, 0.f, 0.f, 0.f};

    #pragma unroll
    for (int ks = 0; ks < 8; ++ks) {
        usx8 ua = *reinterpret_cast<const usx8*>(zrow + ks * 32);
        bf16x8 a = __builtin_bit_cast(bf16x8, ua);
        #pragma unroll
        for (int nt = 0; nt < 4; ++nt) {
            bf16x8 bw = *reinterpret_cast<bf16x8*>(&Bfr[ks][nt][l][0]);
            acc[nt] = __builtin_amdgcn_mfma_f32_16x16x32_bf16(a, bw, acc[nt], 0, 0, 0);
        }
    }
    __syncthreads();   // Bfr reads done; safe to alias tl

    #pragma unroll
    for (int nt = 0; nt < 4; ++nt) {
        int co = nt * 16 + m;               // D col = lane&15
        float bv = bias[co];
        #pragma unroll
        for (int rr = 0; rr < 4; ++rr) {
            int row = i * 16 + quad * 4 + rr; // D row = quad*4+reg
            tl[row][co] = 0.25f * acc[nt][rr] + bv;
        }
    }
    __syncthreads();

    #pragma unroll
    for (int it = 0; it < 16; ++it) {
        int c = i + it * 4;
        out[((size_t)(b * CO_ + c) * T_ + t) * N_ + n0 + l] = tl[l][c];
    }
}

extern "C" void kernel_launch(void* const* d_in, const int* in_sizes, int n_in,
                              void* d_out, int out_size, void* d_ws, size_t ws_size,
                              hipStream_t stream) {
    const float* x       = (const float*)d_in[0];
    const int*   ei      = (const int*)  d_in[1];
    const float* W       = (const float*)d_in[2];
    const float* att_src = (const float*)d_in[3];
    const float* att_dst = (const float*)d_in[4];
    const float* bias    = (const float*)d_in[5];
    float* out = (float*)d_out;

    char* p = (char*)d_ws;
    float* xt      = (float*)p;  p += (size_t)G_ * N_ * C_ * sizeof(float);        // 12.6 MB
    unsigned short* zb = (unsigned short*)p; p += (size_t)G_ * N_ * 256 * sizeof(unsigned short); // 25.2 MB
    float* as_t    = (float*)p;  p += (size_t)H_ * N_ * G_ * sizeof(float);
    float* ad_t    = (float*)p;  p += (size_t)H_ * N_ * G_ * sizeof(float);
    unsigned short* Wfrag = (unsigned short*)p; p += 64 * 256 * sizeof(unsigned short);
    int* off       = (int*)p;    p += 516 * sizeof(int);
    int* srclist   = (int*)p;    p += EP_ * sizeof(int);

    k_prep  <<<385,      512, 0, stream>>>(x, ei, W, att_src, att_dst,
                                           xt, as_t, ad_t, off, srclist, Wfrag);
    k_aggr  <<<8 * 1536, 256, 0, stream>>>(xt, as_t, ad_t, off, srclist, zb);
    k_out   <<<G_ * 8,   256, 0, stream>>>(zb, Wfrag, bias, out);
}